// Round 7
// baseline (425.897 us; speedup 1.0000x reference)
//
#include <hip/hip_runtime.h>
#include <stdint.h>
#include <stddef.h>

typedef int v4i  __attribute__((ext_vector_type(4)));
typedef int v16i __attribute__((ext_vector_type(16)));

struct QParams {
  float s4, z4, s8, z8, sw, zw;
  float s4sw, s8sw;
  int dw;
};

// ---- float <-> orderable uint encoding for atomic min/max ----
__device__ __forceinline__ unsigned enc_f(float f) {
  unsigned u = __float_as_uint(f);
  return (u & 0x80000000u) ? ~u : (u | 0x80000000u);
}
__device__ __forceinline__ float dec_f(unsigned e) {
  unsigned u = (e & 0x80000000u) ? (e ^ 0x80000000u) : ~e;
  return __uint_as_float(u);
}

// ---------------- init: minmax slots + A' zero tails ----------------
__global__ void k_init(unsigned* mm, uint4* t4, uint4* t8) {
  int t = threadIdx.x;
  if (t == 0) { mm[0] = 0xFFFFFFFFu; mm[1] = 0u; mm[2] = 0xFFFFFFFFu; mm[3] = 0u; }
  uint4 z; z.x = z.y = z.z = z.w = 0u;
  t4[t] = z; t4[t + 256] = z;              // 8192 B zero tail for A4'
  t8[t] = z; t8[t + 256] = z;              // 8192 B zero tail for A8'
}

// ---------------- global min/max reduction ----------------
__global__ void k_minmax(const float4* __restrict__ p, int n4, unsigned* mm) {
  float lmin = 3.4e38f, lmax = -3.4e38f;
  for (int i = blockIdx.x * blockDim.x + threadIdx.x; i < n4; i += gridDim.x * blockDim.x) {
    float4 v = p[i];
    lmin = fminf(lmin, fminf(fminf(v.x, v.y), fminf(v.z, v.w)));
    lmax = fmaxf(lmax, fmaxf(fmaxf(v.x, v.y), fmaxf(v.z, v.w)));
  }
  for (int off = 32; off; off >>= 1) {
    lmin = fminf(lmin, __shfl_down(lmin, off, 64));
    lmax = fmaxf(lmax, __shfl_down(lmax, off, 64));
  }
  __shared__ float smin[4], smax[4];
  int w = threadIdx.x >> 6, lane = threadIdx.x & 63;
  if (lane == 0) { smin[w] = lmin; smax[w] = lmax; }
  __syncthreads();
  if (threadIdx.x == 0) {
    float a = fminf(fminf(smin[0], smin[1]), fminf(smin[2], smin[3]));
    float b = fmaxf(fmaxf(smax[0], smax[1]), fmaxf(smax[2], smax[3]));
    atomicMin(&mm[0], enc_f(a));
    atomicMax(&mm[1], enc_f(b));
  }
}

// ---------------- quant params (single thread) ----------------
__global__ void k_params(const unsigned* mm, QParams* q) {
  float xmin = dec_f(mm[0]), xmax = dec_f(mm[1]);
  float wmin = dec_f(mm[2]), wmax = dec_f(mm[3]);
  float s4 = (xmax - xmin) / 15.0f + 1e-7f;
  float z4 = truncf(0.0f - xmin / s4);
  float s8 = (xmax - xmin) / 255.0f + 1e-7f;
  float z8 = truncf(0.0f - xmin / s8);
  float sw = (wmax - wmin) / 255.0f + 1e-7f;
  float zw = truncf(0.0f - wmin / sw);
  q->s4 = s4; q->z4 = z4; q->s8 = s8; q->z8 = z8; q->sw = sw; q->zw = zw;
  q->s4sw = s4 * sw; q->s8sw = s8 * sw;
  q->dw = 128 - (int)zw;   // weight offset correction: true tw = (qw-128) + dw
}

// ---------------- weight quant: OIHW fp32 -> Wc[win][kout][c] i8 (qw-128) ----------------
__global__ void k_quant_w(const float* __restrict__ w, const QParams* __restrict__ q,
                          char* __restrict__ Wc) {
  __shared__ char sm[2304];
  int b = blockIdx.x;                     // kout
  int tid = threadIdx.x;
  float sw = q->sw, zw = q->zw;
  const float* src = w + (size_t)b * 2304;
#pragma unroll
  for (int j = 0; j < 9; ++j) {
    int o = j * 256 + tid;                // coalesced
    float qf = rintf(__fdiv_rn(src[o], sw) + zw);
    qf = fminf(fmaxf(qf, 0.0f), 255.0f);
    int c = o / 9, jj = o - c * 9;        // OIHW: o = c*9 + jj
    sm[jj * 256 + c] = (char)((int)qf - 128);
  }
  __syncthreads();
  if (tid < 64) {
#pragma unroll
    for (int j = 0; j < 9; ++j)
      *(unsigned*)(Wc + (size_t)j * 65536 + b * 256 + tid * 4) =
          *(const unsigned*)(sm + j * 256 + tid * 4);
  }
}

// ---------------- quantize one float to both 4-bit and 8-bit integer codes ----------------
__device__ __forceinline__ void quant2(float v, float s4, float z4, float s8, float z8,
                                       char& o4, char& o8) {
  float q4 = rintf(__fdiv_rn(v, s4) + z4);
  q4 = fminf(fmaxf(q4, 0.0f), 15.0f);
  o4 = (char)(int)(q4 - z4);                   // exact, in [-15,15]
  float q8 = rintf(__fdiv_rn(v, s8) + z8);
  q8 = fminf(fmaxf(q8, 0.0f), 255.0f);
  int t8 = (int)(q8 - z8);
  o8 = (char)max(-128, min(127, t8));          // 128->127: negligible (LSB path only)
}

__device__ __forceinline__ int bsum4(int u) {
  return (int)(signed char)(u & 0xff) + (int)(signed char)((u >> 8) & 0xff)
       + (int)(signed char)((u >> 16) & 0xff) + (int)(signed char)((u >> 24) & 0xff);
}

// ---------------- x quant + NCHW -> MFMA-fragment-order A' + channel sums ----------------
// A'[g = p/32][c16 0..15][m = p%32] * 16B. LDS tile uses 16B-chunk XOR swizzle
// (chunk stored at c16 ^ (px&15)) so phase-1 byte writes are <=4-way.
__global__ void k_quant_x(const float4* __restrict__ x4, const QParams* __restrict__ q,
                          char* __restrict__ A4, char* __restrict__ A8,
                          int* __restrict__ CS4, int* __restrict__ CS8) {
  __shared__ __align__(16) char sm4[56 * 256];
  __shared__ __align__(16) char sm8[56 * 256];
  __shared__ int cp4[56][4], cp8[56][4];
  int bx = blockIdx.x;
  int n = bx / 56, y = bx % 56;
  int tid = threadIdx.x;
  float s4 = q->s4, z4 = q->z4, s8 = q->s8, z8 = q->z8;
  const float4* xrow = x4 + (size_t)n * 200704 + y * 14;
#pragma unroll 2
  for (int it = 0; it < 14; ++it) {
    int idx = it * 256 + tid;                 // < 3584
    int c = idx / 14, xq = idx - c * 14;      // float4 group along x
    float4 v = xrow[(size_t)c * 784 + xq];
    int c16 = c >> 4, cl = c & 15;
    int px0 = xq * 4;
    int s0 = px0 & 15;                        // swizzle base (s0+k never carries, k<4)
    char a0, b0; quant2(v.x, s4, z4, s8, z8, a0, b0);
    char a1, b1; quant2(v.y, s4, z4, s8, z8, a1, b1);
    char a2, b2; quant2(v.z, s4, z4, s8, z8, a2, b2);
    char a3, b3; quant2(v.w, s4, z4, s8, z8, a3, b3);
    int d0 = (px0 + 0) * 256 + ((c16 ^ (s0 + 0)) << 4) + cl;
    int d1 = (px0 + 1) * 256 + ((c16 ^ (s0 + 1)) << 4) + cl;
    int d2 = (px0 + 2) * 256 + ((c16 ^ (s0 + 2)) << 4) + cl;
    int d3 = (px0 + 3) * 256 + ((c16 ^ (s0 + 3)) << 4) + cl;
    sm4[d0] = a0; sm4[d1] = a1; sm4[d2] = a2; sm4[d3] = a3;
    sm8[d0] = b0; sm8[d1] = b1; sm8[d2] = b2; sm8[d3] = b3;
  }
  __syncthreads();
  if (tid < 224) {                            // channel sums (order-free over swizzled row)
    int px = tid >> 2, qq = tid & 3;
    const int* r4 = (const int*)(sm4 + px * 256 + qq * 64);
    const int* r8 = (const int*)(sm8 + px * 256 + qq * 64);
    int a = 0, b = 0;
#pragma unroll
    for (int j = 0; j < 16; ++j) { a += bsum4(r4[j]); b += bsum4(r8[j]); }
    cp4[px][qq] = a; cp8[px][qq] = b;
  }
  __syncthreads();
  int pixbase = n * 3136 + y * 56;
  if (tid < 56) {
    CS4[pixbase + tid] = cp4[tid][0] + cp4[tid][1] + cp4[tid][2] + cp4[tid][3];
    CS8[pixbase + tid] = cp8[tid][0] + cp8[tid][1] + cp8[tid][2] + cp8[tid][3];
  }
  // phase 3: write fragment-order A'. Lanes xc-major -> contiguous m-runs (coalesced).
#pragma unroll
  for (int it = 0; it < 4; ++it) {
    int idx = it * 256 + tid;
    if (idx < 896) {                          // 16 chunks * 56 px
      int c16 = idx / 56, xc = idx - c16 * 56;
      int so = xc * 256 + ((c16 ^ (xc & 15)) << 4);
      v4i v4v = *(const v4i*)(sm4 + so);
      v4i v8v = *(const v4i*)(sm8 + so);
      int pg = pixbase + xc;
      size_t o = (size_t)(pg >> 5) * 8192 + (size_t)c16 * 512 + (size_t)(pg & 31) * 16;
      *(v4i*)(A4 + o) = v4v;
      *(v4i*)(A8 + o) = v8v;
    }
  }
}

// ---------------- 3x3 window sums of channel sums ----------------
__global__ void k_wsum(const int* __restrict__ CS4, const int* __restrict__ CS8,
                       int* __restrict__ S4, int* __restrict__ S8) {
  int p = blockIdx.x * 256 + threadIdx.x;
  if (p >= 100352) return;
  int rem = p % 3136;
  int y = rem / 56, xc = rem % 56;
  int a = 0, b = 0;
#pragma unroll
  for (int dy = -1; dy <= 1; ++dy) {
    if ((unsigned)(y + dy) >= 56u) continue;
#pragma unroll
    for (int dx = -1; dx <= 1; ++dx) {
      if ((unsigned)(xc + dx) >= 56u) continue;
      int qq = p + dy * 56 + dx;
      a += CS4[qq]; b += CS8[qq];
    }
  }
  S4[p] = a; S8[p] = b;
}

// ---------------- fused dual int8 implicit-GEMM conv + epilogue ----------------
#define GLD16(gp, lp)                                                         \
  __builtin_amdgcn_global_load_lds((const __attribute__((address_space(1))) void*)(gp), \
                                   (__attribute__((address_space(3))) void*)(lp), 16, 0, 0)

__device__ __forceinline__ float pg_merge(int a4v, int a8v, float fs4, float fs8) {
  float msb = fs4 * (float)a4v;
  float c8  = fs8 * (float)a8v;
  float lsb = c8 - msb;
  float sig = 1.0f / (1.0f + expf(-msb));
  return msb + (sig > 0.99f ? lsb : 0.0f);
}

struct Frag { v4i a4k0, a4k1, a8k0, a8k1; };

// issue one K-stage: 2 B global_load_lds + 4 plain A-frag loads.
// No manual vmcnt anywhere in this kernel: __syncthreads() (full
// vmcnt(0)+lgkmcnt(0) drain + barrier) provides RAW and WAR safety by
// construction. (Rounds 3-6 bug class: raw s_barrier without lgkmcnt drain
// let compiler-sunk ds_read consumers escape the barrier window.)
#define ISSUE(S, DB, F)                                                        \
  {                                                                            \
    const int s_ = (S);                                                        \
    const int win_ = s_ >> 2;                                                  \
    const int cs_ = s_ & 3;                                                    \
    const char* bsrc_ = gB + win_ * 65536 + cs_ * 64;                          \
    GLD16(bsrc_, (DB));                                                        \
    GLD16(bsrc_ + 4096, (DB) + 1024);                                          \
    unsigned ao_ = vofs[win_] + (unsigned)(cs_ << 11);                         \
    (F).a4k0 = *(const v4i*)(A4 + ao_);                                        \
    (F).a4k1 = *(const v4i*)(A4 + ao_ + 1024);                                 \
    (F).a8k0 = *(const v4i*)(A8 + ao_);                                        \
    (F).a8k1 = *(const v4i*)(A8 + ao_ + 1024);                                 \
  }

#define COMPUTE(BUF, F)                                                        \
  {                                                                            \
    _Pragma("unroll")                                                          \
    for (int kc = 0; kc < 2; ++kc) {                                           \
      v4i bf[4];                                                               \
      _Pragma("unroll")                                                        \
      for (int fn = 0; fn < 4; ++fn)                                           \
        bf[fn] = *(const v4i*)((const char*)smB + (BUF) * 8192 + offB[fn][kc]);\
      v4i a4_ = kc ? (F).a4k1 : (F).a4k0;                                      \
      v4i a8_ = kc ? (F).a8k1 : (F).a8k0;                                      \
      _Pragma("unroll")                                                        \
      for (int fn = 0; fn < 4; ++fn) {                                         \
        acc4[fn] = __builtin_amdgcn_mfma_i32_32x32x32_i8(a4_, bf[fn], acc4[fn], 0, 0, 0); \
        acc8[fn] = __builtin_amdgcn_mfma_i32_32x32x32_i8(a8_, bf[fn], acc8[fn], 0, 0, 0); \
      }                                                                        \
    }                                                                          \
  }

__global__ __launch_bounds__(256, 2) void k_conv(
    const char* __restrict__ A4, const char* __restrict__ A8,
    const char* __restrict__ Wc,
    const int* __restrict__ S4, const int* __restrict__ S8,
    const QParams* __restrict__ q,
    float* __restrict__ out) {
  __shared__ char smB[2][8192];                 // B double buffer (16 KB)
  const unsigned ASZ = 25690112u;               // zero tail lives at [ASZ, ASZ+8192)
  int tid = threadIdx.x;
  int w = tid >> 6, lane = tid & 63;
  int l31 = lane & 31, qh = lane >> 5;
  int m0 = blockIdx.x * 128;                    // pixel tile
  int n0 = blockIdx.y * 128;                    // kout tile

  // ---- per-lane A voffsets per window (OOB -> zero-tail offset) ----
  int p = m0 + w * 32 + l31;                    // this lane's pixel row
  int rem = p % 3136;
  int y = rem / 56, x = rem % 56;
  unsigned zoff = ASZ + (unsigned)(qh * 512 + l31 * 16);
  unsigned vofs[9];
#pragma unroll
  for (int win = 0; win < 9; ++win) {
    int dy = win / 3 - 1, dx = win % 3 - 1;
    bool ok = ((unsigned)(y + dy) < 56u) && ((unsigned)(x + dx) < 56u);
    int mp = p + dy * 56 + dx;
    vofs[win] = ok ? ((((unsigned)mp >> 5) << 13) | ((unsigned)qh << 9) |
                     (((unsigned)mp & 31u) << 4))
                   : zoff;
  }

  // ---- B staging: wave w stages kout rows [w*32, w*32+32) ----
  int r0 = w * 32 + (lane >> 2);
  int chunk = lane & 3;
  int cg = chunk ^ ((r0 >> 1) & 3);             // XOR swizzle on source side
  const char* gB = Wc + (n0 + r0) * 256 + cg * 16;
  char* dB0 = &smB[0][w * 2048];
  char* dB1 = &smB[1][w * 2048];

  // ---- B LDS read offsets (swizzle folded) ----
  int offB[4][2];
#pragma unroll
  for (int fn = 0; fn < 4; ++fn) {
    int row = fn * 32 + l31;
    int swz = (row >> 1) & 3;
#pragma unroll
    for (int kc = 0; kc < 2; ++kc)
      offB[fn][kc] = row * 64 + (((kc * 2 + qh) ^ swz) << 4);
  }

  v16i acc4[4] = {}, acc8[4] = {};
  Frag F0, F1;

  // ---- pipeline: issue s+1, compute s, __syncthreads() ----
  // __syncthreads drains vmcnt(0)+lgkmcnt(0): stage-s+1 loads (issued before
  // the compute phase) land during COMPUTE(s); buffer (s+1)&1's readers all
  // completed before the previous barrier. Correct by construction.
  ISSUE(0, dB0, F0);
  __syncthreads();
#pragma unroll
  for (int s = 0; s < 36; ++s) {
    if (s + 1 < 36) {
      if ((s & 1) == 0) { ISSUE(s + 1, dB1, F1); }
      else              { ISSUE(s + 1, dB0, F0); }
    }
    if ((s & 1) == 0) { COMPUTE(0, F0); }
    else              { COMPUTE(1, F1); }
    __syncthreads();
  }

  // -------- epilogue: exact offset correction, scale, sigmoid gate, NCHW store --------
  float fs4 = q->s4sw, fs8 = q->s8sw;
  int dwv = q->dw;
  int pb = m0 + w * 32 + 4 * qh;
#pragma unroll
  for (int fn = 0; fn < 4; ++fn) {
    int kout = n0 + fn * 32 + l31;
#pragma unroll
    for (int rg = 0; rg < 4; ++rg) {
      int pr = pb + 8 * rg;                     // 4 consecutive pixels, never cross image
      int4 sv4 = *(const int4*)(S4 + pr);
      int4 sv8 = *(const int4*)(S8 + pr);
      float4 res;
      res.x = pg_merge(acc4[fn][rg * 4 + 0] + dwv * sv4.x,
                       acc8[fn][rg * 4 + 0] + dwv * sv8.x, fs4, fs8);
      res.y = pg_merge(acc4[fn][rg * 4 + 1] + dwv * sv4.y,
                       acc8[fn][rg * 4 + 1] + dwv * sv8.y, fs4, fs8);
      res.z = pg_merge(acc4[fn][rg * 4 + 2] + dwv * sv4.z,
                       acc8[fn][rg * 4 + 2] + dwv * sv8.z, fs4, fs8);
      res.w = pg_merge(acc4[fn][rg * 4 + 3] + dwv * sv4.w,
                       acc8[fn][rg * 4 + 3] + dwv * sv8.w, fs4, fs8);
      int nimg = pr / 3136;
      int rr = pr - nimg * 3136;
      *(float4*)(out + (size_t)nimg * 802816 + (size_t)kout * 3136 + rr) = res;
    }
  }
}

// ---------------- launch ----------------
extern "C" void kernel_launch(void* const* d_in, const int* in_sizes, int n_in,
                              void* d_out, int out_size, void* d_ws, size_t ws_size,
                              hipStream_t stream) {
  const float* x  = (const float*)d_in[0];
  const float* wt = (const float*)d_in[1];
  float* out = (float*)d_out;

  char* ws = (char*)d_ws;
  unsigned* mm = (unsigned*)ws;                 // 4 minmax slots
  QParams* prm = (QParams*)(ws + 64);
  char* A4 = ws + 1024;                         // fragment-order A' (+8K zero tail)
  const size_t ASZ = 25690112;                  // 32*56*56*256
  char* A8 = A4 + ASZ + 8192;                   // fragment-order A8' (+8K zero tail)
  int* CS4 = (int*)(A8 + ASZ + 8192);
  int* CS8 = CS4 + 100352;
  int* S4  = CS8 + 100352;
  int* S8  = S4 + 100352;
  char* Wc = (char*)(S8 + 100352);              // 9*65536 bytes; total ~53.6 MB

  k_init<<<1, 256, 0, stream>>>(mm, (uint4*)(A4 + ASZ), (uint4*)(A8 + ASZ));
  k_minmax<<<1024, 256, 0, stream>>>((const float4*)x, 25690112 / 4, mm);
  k_minmax<<<64, 256, 0, stream>>>((const float4*)wt, 589824 / 4, mm + 2);
  k_params<<<1, 1, 0, stream>>>(mm, prm);
  k_quant_w<<<256, 256, 0, stream>>>(wt, prm, Wc);
  k_quant_x<<<1792, 256, 0, stream>>>((const float4*)x, prm, A4, A8, CS4, CS8);
  k_wsum<<<392, 256, 0, stream>>>(CS4, CS8, S4, S8);
  k_conv<<<dim3(784, 2), 256, 0, stream>>>(A4, A8, Wc, S4, S8, prm, out);
}